// Round 16
// baseline (344.470 us; speedup 1.0000x reference)
//
#include <hip/hip_runtime.h>
#include <cstdint>

#define BN 2
#define HN 16
#define NN 2048
#define DD 64
#define KT 64
#define NT (NN / KT)     // 32 tiles
#define QB 128           // q-rows per block (8 waves x 16)
#define LDP 72           // bf16 LDS row stride (Kb)
#define LDF 68           // fp32 LDS row stride (Pb)
#define KVELEMS ((size_t)BN * HN * NN * DD)   // bf16 elems of V^T in ws (8.4 MB)

typedef __attribute__((ext_vector_type(8))) short short8;
typedef __attribute__((ext_vector_type(2))) uint32_t uint2v;
typedef __attribute__((ext_vector_type(4))) uint32_t uint4v;
typedef __attribute__((ext_vector_type(4))) float float4v;

// packed f32->bf16 (RTNE), 2 elems / instr
static __device__ __forceinline__ uint32_t cvt_pk_bf16(float a, float b){
    uint32_t r;
    asm("v_cvt_pk_bf16_f32 %0, %1, %2" : "=v"(r) : "v"(a), "v"(b));
    return r;
}
static __device__ __forceinline__ unsigned short f2bf1(float a){
    return (unsigned short)(cvt_pk_bf16(a, a) & 0xffffu);
}
static __device__ __forceinline__ short8 pack8(float4v f0, float4v f1){
    uint4v u;
    u[0] = cvt_pk_bf16(f0[0], f0[1]);
    u[1] = cvt_pk_bf16(f0[2], f0[3]);
    u[2] = cvt_pk_bf16(f1[0], f1[1]);
    u[3] = cvt_pk_bf16(f1[2], f1[3]);
    return __builtin_bit_cast(short8, u);
}

static __device__ __forceinline__ float4v mfma_bf16(short8 a, short8 b, float4v c){
    return __builtin_amdgcn_mfma_f32_16x16x32_bf16(a, b, c, 0, 0, 0);
}

// Raw barrier: drain LDS ops only; global loads/stores stay in flight.
static __device__ __forceinline__ void barrier_lds(){
    asm volatile("s_waitcnt lgkmcnt(0)" ::: "memory");
    __builtin_amdgcn_s_barrier();
    asm volatile("" ::: "memory");
}
static __device__ __forceinline__ void lgkm_drain(){
    asm volatile("s_waitcnt lgkmcnt(0)" ::: "memory");
}

// ===== pre-pass: V (fp32 [bh][kv][d]) -> V^T bf16 [bh][d][kv]  (verified R11) =====
__global__ void transpose_v_kernel(const float* __restrict__ V,
                                   unsigned short* __restrict__ VTW){
    __shared__ unsigned short T[64][72];
    const int bid = blockIdx.x;
    const int bh  = bid >> 5;
    const int ct  = bid & 31;
    const int tid = threadIdx.x;

    const float* src = V + ((size_t)bh * NN + ct * 64) * DD;
    const int srow = tid >> 4;
    const int scol = (tid & 15) << 2;
    #pragma unroll
    for(int i = 0; i < 4; ++i){
        const int row = srow + 16 * i;
        float4v f = *(const float4v*)(src + (size_t)row * DD + scol);
        #pragma unroll
        for(int j = 0; j < 4; ++j)
            T[scol + j][row] = f2bf1(f[j]);
    }
    __syncthreads();
    unsigned short* dst = VTW + (size_t)bh * DD * NN + ct * 64;
    const int d  = tid >> 2;
    const int kc = (tid & 3) << 4;
    *(uint4v*)(dst + (size_t)d * NN + kc)     = *(const uint4v*)&T[d][kc];
    *(uint4v*)(dst + (size_t)d * NN + kc + 8) = *(const uint4v*)&T[d][kc + 8];
}

// 512 threads, 2 blocks/CU. VGPR cap 128 (R9 lesson: never force below natural).
__launch_bounds__(512, 4)
__global__ void attn_fused_kernel(const float* __restrict__ Q,
                                  const float* __restrict__ K,
                                  const float* __restrict__ V,
                                  const float* __restrict__ Bias,
                                  const unsigned short* __restrict__ VTW,
                                  float* __restrict__ Out){
    __shared__ unsigned short Kb[2][KT][LDP];   // double-buffered K tile [kv][d]
    __shared__ float Pb[8][16][LDF];            // per-wave bias/P bounce (fp32, wave-private)

    // XCD-aware decode: slot raw&7 owns 2 whole heads (bias/K/V^T L2-resident).
    const int raw  = blockIdx.x;
    const int slot = raw & 7;
    const int idx  = raw >> 3;            // 0..63
    const int h    = slot * 2 + (idx >> 5);
    const int rem  = idx & 31;
    const int b    = rem & 1;             // batch pair adjacent -> shares bias slice
    const int rt   = rem >> 1;            // 0..15

    const int tid = threadIdx.x;
    const int l   = tid & 63;
    const int w   = tid >> 6;             // wave 0..7
    const int lg  = l >> 4;               // acc-layout row group
    const int ll  = l & 15;               // acc-layout col
    const int vc  = ll * 4;               // vec-layout col

    // staging coords: wave instr = 4 rows x 256B
    const int srow = tid >> 4;            // 0..31
    const int scol = (tid & 15) << 2;     // element col

    const int qw = rt * QB + w * 16;
    const size_t bh = (size_t)(b * HN + h);
    const float* Qg = Q + (bh * NN + qw) * DD;
    const float* Kg = K + bh * NN * DD;
    // V^T fragment base: lane covers d = ds*16+ll, kv = ct*64 + ks*32 + lg*8 (+0..7)
    const unsigned short* vtF = VTW + bh * DD * NN + (size_t)ll * NN + lg * 8;
    // vec-layout bias base: lane covers rows qw+lg+4*it, cols vc..vc+3
    const float* BgV = Bias + (size_t)h * NN * NN + (size_t)(qw + lg) * NN + vc;

    // ---- Q fragments (A-frag: row=ll, k=ks*32+lg*8+j) ----
    short8 qf[2];
    {
        const float* qrow = Qg + (size_t)ll * DD + lg * 8;
        #pragma unroll
        for(int ks = 0; ks < 2; ++ks)
            qf[ks] = pack8(*(const float4v*)(qrow + ks * 32),
                           *(const float4v*)(qrow + ks * 32 + 4));
    }

    float lsum[4];
    #pragma unroll
    for(int r = 0; r < 4; ++r) lsum[r] = 0.f;

    // =============== PASS 1: row sums; Kb double-buffered, 1 barrier/tile ===============
    float4v kreg[2], bv[4];
    #pragma unroll
    for(int i = 0; i < 2; ++i)
        kreg[i] = *(const float4v*)(Kg + (size_t)(srow + 32*i) * DD + scol);
    #pragma unroll
    for(int i = 0; i < 2; ++i){            // stage tile 0 -> buf 0
        uint2v t = { cvt_pk_bf16(kreg[i][0], kreg[i][1]),
                     cvt_pk_bf16(kreg[i][2], kreg[i][3]) };
        *(uint2v*)&Kb[0][srow + 32*i][scol] = t;
    }
    #pragma unroll
    for(int i = 0; i < 2; ++i)             // load tile 1
        kreg[i] = *(const float4v*)(Kg + (size_t)(KT + srow + 32*i) * DD + scol);
    #pragma unroll
    for(int it = 0; it < 4; ++it)
        bv[it] = *(const float4v*)(BgV + (size_t)(it * 4) * NN);
    barrier_lds();

    for(int ct = 0; ct < NT; ++ct){
        const int cur = ct & 1;
        if(ct + 1 < NT){                   // stage t+1 into other buffer
            #pragma unroll
            for(int i = 0; i < 2; ++i){
                uint2v t = { cvt_pk_bf16(kreg[i][0], kreg[i][1]),
                             cvt_pk_bf16(kreg[i][2], kreg[i][3]) };
                *(uint2v*)&Kb[cur ^ 1][srow + 32*i][scol] = t;
            }
        }
        if(ct + 2 < NT){                   // load t+2
            #pragma unroll
            for(int i = 0; i < 2; ++i)
                kreg[i] = *(const float4v*)(Kg + (size_t)((ct+2)*KT + srow + 32*i) * DD + scol);
        }
        #pragma unroll
        for(int it = 0; it < 4; ++it)      // stage bias(t) (Pb wave-private)
            *(float4v*)&Pb[w][it*4 + lg][vc] = bv[it];
        if(ct + 1 < NT){
            #pragma unroll
            for(int it = 0; it < 4; ++it)
                bv[it] = *(const float4v*)(BgV + (size_t)(it * 4) * NN + (ct+1)*KT);
        }

        float4v acc[4];
        #pragma unroll
        for(int sub = 0; sub < 4; ++sub) acc[sub] = (float4v){0.f,0.f,0.f,0.f};
        __builtin_amdgcn_s_setprio(1);
        #pragma unroll
        for(int sub = 0; sub < 4; ++sub){
            short8 b0 = *(const short8*)&Kb[cur][sub*16 + ll][lg*8];
            short8 b1 = *(const short8*)&Kb[cur][sub*16 + ll][32 + lg*8];
            acc[sub] = mfma_bf16(qf[0], b0, acc[sub]);
            acc[sub] = mfma_bf16(qf[1], b1, acc[sub]);
        }
        __builtin_amdgcn_s_setprio(0);

        #pragma unroll
        for(int r = 0; r < 4; ++r){
            float e0 = __expf(acc[0][r] * 0.125f + Pb[w][lg*4+r][      ll]);
            float e1 = __expf(acc[1][r] * 0.125f + Pb[w][lg*4+r][16 +  ll]);
            float e2 = __expf(acc[2][r] * 0.125f + Pb[w][lg*4+r][32 +  ll]);
            float e3 = __expf(acc[3][r] * 0.125f + Pb[w][lg*4+r][48 +  ll]);
            lsum[r] += (e0 + e1) + (e2 + e3);
        }
        barrier_lds();                     // publishes buf[cur^1]
    }

    float rl[4];
    #pragma unroll
    for(int r = 0; r < 4; ++r){
        #pragma unroll
        for(int d = 1; d < 16; d <<= 1) lsum[r] += __shfl_xor(lsum[r], d);
        rl[r] = 1.0f / lsum[r];
    }

    // ========= PASS 2: V^T frags direct from L2 (ws); Kb dbuf, 1 barrier/tile =========
    float4v oacc[4];
    #pragma unroll
    for(int ds = 0; ds < 4; ++ds) oacc[ds] = (float4v){0.f,0.f,0.f,0.f};

    float* attnW = Out + (size_t)BN*HN*NN*DD
                 + (bh * NN + qw + lg) * (size_t)NN + vc;

    #pragma unroll
    for(int i = 0; i < 2; ++i)
        kreg[i] = *(const float4v*)(Kg + (size_t)(srow + 32*i) * DD + scol);
    #pragma unroll
    for(int i = 0; i < 2; ++i){            // stage tile 0 -> buf 0
        uint2v t = { cvt_pk_bf16(kreg[i][0], kreg[i][1]),
                     cvt_pk_bf16(kreg[i][2], kreg[i][3]) };
        *(uint2v*)&Kb[0][srow + 32*i][scol] = t;
    }
    #pragma unroll
    for(int i = 0; i < 2; ++i)             // load tile 1
        kreg[i] = *(const float4v*)(Kg + (size_t)(KT + srow + 32*i) * DD + scol);
    #pragma unroll
    for(int it = 0; it < 4; ++it)
        bv[it] = *(const float4v*)(BgV + (size_t)(it * 4) * NN);
    barrier_lds();

    for(int ct = 0; ct < NT; ++ct){
        const int cur = ct & 1;
        if(ct + 1 < NT){                   // stage K t+1
            #pragma unroll
            for(int i = 0; i < 2; ++i){
                uint2v t = { cvt_pk_bf16(kreg[i][0], kreg[i][1]),
                             cvt_pk_bf16(kreg[i][2], kreg[i][3]) };
                *(uint2v*)&Kb[cur ^ 1][srow + 32*i][scol] = t;
            }
        }
        if(ct + 2 < NT){                   // load K t+2
            #pragma unroll
            for(int i = 0; i < 2; ++i)
                kreg[i] = *(const float4v*)(Kg + (size_t)((ct+2)*KT + srow + 32*i) * DD + scol);
        }
        #pragma unroll
        for(int it = 0; it < 4; ++it)      // stage bias(t) (wave-private)
            *(float4v*)&Pb[w][it*4 + lg][vc] = bv[it];
        if(ct + 1 < NT){
            #pragma unroll
            for(int it = 0; it < 4; ++it)
                bv[it] = *(const float4v*)(BgV + (size_t)(it * 4) * NN + (ct+1)*KT);
        }

        // V^T fragments for tile t: 8 x dwordx4 from ws (L2-resident with XCD pinning);
        // issued BEFORE the QK MFMA so L2 latency hides under MFMA + softmax.
        short8 vf[8];
        #pragma unroll
        for(int ds = 0; ds < 4; ++ds)
            #pragma unroll
            for(int ks = 0; ks < 2; ++ks)
                vf[ds*2+ks] = __builtin_bit_cast(short8,
                    *(const uint4v*)(vtF + (size_t)(ds*16) * NN + ct*KT + ks*32));

        float4v acc[4];
        #pragma unroll
        for(int sub = 0; sub < 4; ++sub) acc[sub] = (float4v){0.f,0.f,0.f,0.f};
        __builtin_amdgcn_s_setprio(1);
        #pragma unroll
        for(int sub = 0; sub < 4; ++sub){
            short8 b0 = *(const short8*)&Kb[cur][sub*16 + ll][lg*8];
            short8 b1 = *(const short8*)&Kb[cur][sub*16 + ll][32 + lg*8];
            acc[sub] = mfma_bf16(qf[0], b0, acc[sub]);
            acc[sub] = mfma_bf16(qf[1], b1, acc[sub]);
        }
        __builtin_amdgcn_s_setprio(0);

        // ---- K-half pipelined softmax/PV bridge ----
        #pragma unroll
        for(int sub = 0; sub < 2; ++sub)
            #pragma unroll
            for(int r = 0; r < 4; ++r){
                float sv = acc[sub][r] * 0.125f + Pb[w][lg*4+r][sub*16+ll];
                Pb[w][lg*4+r][sub*16+ll] = __expf(sv) * rl[r];
            }
        lgkm_drain();

        short8 pf0;
        {
            float4v p0 = *(const float4v*)&Pb[w][ll][lg*8];
            float4v p1 = *(const float4v*)&Pb[w][ll][lg*8 + 4];
            pf0 = pack8(p0, p1);
        }
        #pragma unroll
        for(int sub = 2; sub < 4; ++sub)
            #pragma unroll
            for(int r = 0; r < 4; ++r){
                float sv = acc[sub][r] * 0.125f + Pb[w][lg*4+r][sub*16+ll];
                Pb[w][lg*4+r][sub*16+ll] = __expf(sv) * rl[r];
            }

        // PV kb=0 while subs 2,3 softmax retires
        __builtin_amdgcn_s_setprio(1);
        #pragma unroll
        for(int ds = 0; ds < 4; ++ds)
            oacc[ds] = mfma_bf16(pf0, vf[ds*2+0], oacc[ds]);
        __builtin_amdgcn_s_setprio(0);
        lgkm_drain();

        short8 pf1;
        {
            float4v p2 = *(const float4v*)&Pb[w][ll][32 + lg*8];
            float4v p3 = *(const float4v*)&Pb[w][ll][32 + lg*8 + 4];
            pf1 = pack8(p2, p3);
        }
        __builtin_amdgcn_s_setprio(1);
        #pragma unroll
        for(int ds = 0; ds < 4; ++ds)
            oacc[ds] = mfma_bf16(pf1, vf[ds*2+1], oacc[ds]);
        __builtin_amdgcn_s_setprio(0);

        // attn store last: all 64 cols of Pb hold p (drained above)
        #pragma unroll
        for(int it = 0; it < 4; ++it){
            float4v pv = *(const float4v*)&Pb[w][it*4 + lg][vc];
            *(float4v*)(attnW + (size_t)(it*4) * NN + ct*KT) = pv;
        }

        barrier_lds();                     // publishes Kb[cur^1]
    }

    // O store
    float* outG = Out + (bh * NN + qw) * (size_t)DD;
    #pragma unroll
    for(int ds = 0; ds < 4; ++ds)
        #pragma unroll
        for(int r = 0; r < 4; ++r)
            outG[(size_t)(lg*4 + r) * DD + ds*16 + ll] = oacc[ds][r];
}

extern "C" void kernel_launch(void* const* d_in, const int* in_sizes, int n_in,
                              void* d_out, int out_size, void* d_ws, size_t ws_size,
                              hipStream_t stream) {
    const float* q    = (const float*)d_in[0];
    const float* k    = (const float*)d_in[1];
    const float* v    = (const float*)d_in[2];
    const float* bias = (const float*)d_in[3];
    float* out = (float*)d_out;
    unsigned short* vtw = (unsigned short*)d_ws;   // 8.4 MB (ws >= 16.8 MB verified R11)

    hipLaunchKernelGGL(transpose_v_kernel, dim3(BN * HN * (NN / 64)), dim3(256), 0, stream,
                       v, vtw);
    hipLaunchKernelGGL(attn_fused_kernel, dim3(BN * HN * (NN / QB)), dim3(512), 0, stream,
                       q, k, v, bias, vtw, out);
}

// Round 17
// 320.667 us; speedup vs baseline: 1.0742x; 1.0742x over previous
//
#include <hip/hip_runtime.h>
#include <cstdint>

#define BN 2
#define HN 16
#define NN 2048
#define DD 64
#define KT 64
#define NT (NN / KT)     // 32 tiles
#define QB 128           // q-rows per block (8 waves x 16)
#define LDP 72           // bf16 LDS row stride (Kb)
#define LDF 68           // fp32 LDS row stride (Pb)

typedef __attribute__((ext_vector_type(8))) short short8;
typedef __attribute__((ext_vector_type(2))) uint32_t uint2v;
typedef __attribute__((ext_vector_type(4))) uint32_t uint4v;
typedef __attribute__((ext_vector_type(4))) float float4v;

// packed f32->bf16 (RTNE), 2 elems / instr
static __device__ __forceinline__ uint32_t cvt_pk_bf16(float a, float b){
    uint32_t r;
    asm("v_cvt_pk_bf16_f32 %0, %1, %2" : "=v"(r) : "v"(a), "v"(b));
    return r;
}
static __device__ __forceinline__ unsigned short f2bf1(float a){
    return (unsigned short)(cvt_pk_bf16(a, a) & 0xffffu);
}
static __device__ __forceinline__ short8 pack8(float4v f0, float4v f1){
    uint4v u;
    u[0] = cvt_pk_bf16(f0[0], f0[1]);
    u[1] = cvt_pk_bf16(f0[2], f0[3]);
    u[2] = cvt_pk_bf16(f1[0], f1[1]);
    u[3] = cvt_pk_bf16(f1[2], f1[3]);
    return __builtin_bit_cast(short8, u);
}

static __device__ __forceinline__ float4v mfma_bf16(short8 a, short8 b, float4v c){
    return __builtin_amdgcn_mfma_f32_16x16x32_bf16(a, b, c, 0, 0, 0);
}

// Raw barrier: drain LDS ops only; global loads/stores stay in flight.
static __device__ __forceinline__ void barrier_lds(){
    asm volatile("s_waitcnt lgkmcnt(0)" ::: "memory");
    __builtin_amdgcn_s_barrier();
    asm volatile("" ::: "memory");
}
static __device__ __forceinline__ void lgkm_drain(){
    asm volatile("s_waitcnt lgkmcnt(0)" ::: "memory");
}

// ===== pre-pass: V (fp32 [bh][kv][d]) -> V^T bf16 in MFMA B-FRAG layout =====
// ws layout: [(bh*32+ct)*8 + s][lane 0..63][8 bf16], s = ds*2+ks.
// Lane l=(lg,ll) of slot s holds V^T[d=ds*16+ll][kv=ct*64+ks*32+lg*8 .. +7].
// Main kernel's fragment load is then 64 lanes x 16B CONTIGUOUS (1KB).
__global__ void transpose_v_frag(const float* __restrict__ V,
                                 unsigned short* __restrict__ VTW){
    __shared__ unsigned short T[64][72];
    const int bid = blockIdx.x;
    const int bh  = bid >> 5;
    const int ct  = bid & 31;
    const int tid = threadIdx.x;

    const float* src = V + ((size_t)bh * NN + ct * 64) * DD;
    const int srow = tid >> 4;
    const int scol = (tid & 15) << 2;
    #pragma unroll
    for(int i = 0; i < 4; ++i){
        const int row = srow + 16 * i;
        float4v f = *(const float4v*)(src + (size_t)row * DD + scol);
        #pragma unroll
        for(int j = 0; j < 4; ++j)
            T[scol + j][row] = f2bf1(f[j]);
    }
    __syncthreads();

    const int w4 = tid >> 6;          // wave 0..3 -> slots 2w4, 2w4+1
    const int l  = tid & 63;
    const int lg = l >> 4;
    const int ll = l & 15;
    unsigned short* dstBase = VTW + ((size_t)(bh * 32 + ct) * 8) * 512;
    #pragma unroll
    for(int si = 0; si < 2; ++si){
        const int s  = w4 * 2 + si;
        const int ds = s >> 1;
        const int ks = s & 1;
        uint4v val = *(const uint4v*)&T[ds*16 + ll][ks*32 + lg*8];
        *(uint4v*)(dstBase + ((size_t)s * 64 + l) * 8) = val;
    }
}

// 512 threads, 2 blocks/CU (grid-capped). VGPR cap 128 (R9 lesson).
__launch_bounds__(512, 4)
__global__ void attn_fused_kernel(const float* __restrict__ Q,
                                  const float* __restrict__ K,
                                  const float* __restrict__ Bias,
                                  const unsigned short* __restrict__ VTW,
                                  float* __restrict__ Out){
    __shared__ unsigned short Kb[2][KT][LDP];   // double-buffered K tile [kv][d]
    __shared__ float Pb[8][16][LDF];            // per-wave bias/P bounce (fp32, wave-private)

    // XCD-aware decode: slot raw&7 owns 2 whole heads (bias/K/V^T L2-resident).
    const int raw  = blockIdx.x;
    const int slot = raw & 7;
    const int idx  = raw >> 3;            // 0..63
    const int h    = slot * 2 + (idx >> 5);
    const int rem  = idx & 31;
    const int b    = rem & 1;             // batch pair adjacent -> shares bias slice
    const int rt   = rem >> 1;            // 0..15

    const int tid = threadIdx.x;
    const int l   = tid & 63;
    const int w   = tid >> 6;             // wave 0..7
    const int lg  = l >> 4;               // acc-layout row group
    const int ll  = l & 15;               // acc-layout col
    const int vc  = ll * 4;               // vec-layout col

    // staging coords: wave instr = 4 rows x 256B
    const int srow = tid >> 4;            // 0..31
    const int scol = (tid & 15) << 2;     // element col

    const int qw = rt * QB + w * 16;
    const size_t bh = (size_t)(b * HN + h);
    const float* Qg = Q + (bh * NN + qw) * DD;
    const float* Kg = K + bh * NN * DD;
    // frag-layout V^T base: this lane's 16B within each slot
    const unsigned short* vtB = VTW + (size_t)bh * 32 * 4096 + (size_t)l * 8;
    // vec-layout bias base: lane covers rows qw+lg+4*it, cols vc..vc+3
    const float* BgV = Bias + (size_t)h * NN * NN + (size_t)(qw + lg) * NN + vc;

    // ---- Q fragments (A-frag: row=ll, k=ks*32+lg*8+j) ----
    short8 qf[2];
    {
        const float* qrow = Qg + (size_t)ll * DD + lg * 8;
        #pragma unroll
        for(int ks = 0; ks < 2; ++ks)
            qf[ks] = pack8(*(const float4v*)(qrow + ks * 32),
                           *(const float4v*)(qrow + ks * 32 + 4));
    }

    float lsum[4];
    #pragma unroll
    for(int r = 0; r < 4; ++r) lsum[r] = 0.f;

    // =============== PASS 1: row sums; Kb double-buffered, 1 barrier/tile ===============
    float4v kreg[2], bv[4];
    #pragma unroll
    for(int i = 0; i < 2; ++i)
        kreg[i] = *(const float4v*)(Kg + (size_t)(srow + 32*i) * DD + scol);
    #pragma unroll
    for(int i = 0; i < 2; ++i){            // stage tile 0 -> buf 0
        uint2v t = { cvt_pk_bf16(kreg[i][0], kreg[i][1]),
                     cvt_pk_bf16(kreg[i][2], kreg[i][3]) };
        *(uint2v*)&Kb[0][srow + 32*i][scol] = t;
    }
    #pragma unroll
    for(int i = 0; i < 2; ++i)             // load tile 1
        kreg[i] = *(const float4v*)(Kg + (size_t)(KT + srow + 32*i) * DD + scol);
    #pragma unroll
    for(int it = 0; it < 4; ++it)
        bv[it] = *(const float4v*)(BgV + (size_t)(it * 4) * NN);
    barrier_lds();

    for(int ct = 0; ct < NT; ++ct){
        const int cur = ct & 1;
        if(ct + 1 < NT){                   // stage t+1 into other buffer
            #pragma unroll
            for(int i = 0; i < 2; ++i){
                uint2v t = { cvt_pk_bf16(kreg[i][0], kreg[i][1]),
                             cvt_pk_bf16(kreg[i][2], kreg[i][3]) };
                *(uint2v*)&Kb[cur ^ 1][srow + 32*i][scol] = t;
            }
        }
        if(ct + 2 < NT){                   // load t+2
            #pragma unroll
            for(int i = 0; i < 2; ++i)
                kreg[i] = *(const float4v*)(Kg + (size_t)((ct+2)*KT + srow + 32*i) * DD + scol);
        }
        #pragma unroll
        for(int it = 0; it < 4; ++it)      // stage bias(t) (Pb wave-private)
            *(float4v*)&Pb[w][it*4 + lg][vc] = bv[it];
        if(ct + 1 < NT){
            #pragma unroll
            for(int it = 0; it < 4; ++it)
                bv[it] = *(const float4v*)(BgV + (size_t)(it * 4) * NN + (ct+1)*KT);
        }

        float4v acc[4];
        #pragma unroll
        for(int sub = 0; sub < 4; ++sub) acc[sub] = (float4v){0.f,0.f,0.f,0.f};
        __builtin_amdgcn_s_setprio(1);
        #pragma unroll
        for(int sub = 0; sub < 4; ++sub){
            short8 b0 = *(const short8*)&Kb[cur][sub*16 + ll][lg*8];
            short8 b1 = *(const short8*)&Kb[cur][sub*16 + ll][32 + lg*8];
            acc[sub] = mfma_bf16(qf[0], b0, acc[sub]);
            acc[sub] = mfma_bf16(qf[1], b1, acc[sub]);
        }
        __builtin_amdgcn_s_setprio(0);

        #pragma unroll
        for(int r = 0; r < 4; ++r){
            float e0 = __expf(acc[0][r] * 0.125f + Pb[w][lg*4+r][      ll]);
            float e1 = __expf(acc[1][r] * 0.125f + Pb[w][lg*4+r][16 +  ll]);
            float e2 = __expf(acc[2][r] * 0.125f + Pb[w][lg*4+r][32 +  ll]);
            float e3 = __expf(acc[3][r] * 0.125f + Pb[w][lg*4+r][48 +  ll]);
            lsum[r] += (e0 + e1) + (e2 + e3);
        }
        barrier_lds();                     // publishes buf[cur^1]
    }

    float rl[4];
    #pragma unroll
    for(int r = 0; r < 4; ++r){
        #pragma unroll
        for(int d = 1; d < 16; d <<= 1) lsum[r] += __shfl_xor(lsum[r], d);
        rl[r] = 1.0f / lsum[r];
    }

    // ===== PASS 2: V^T frags from ws (frag layout, 1KB coalesced); Kb dbuf =====
    float4v oacc[4];
    #pragma unroll
    for(int ds = 0; ds < 4; ++ds) oacc[ds] = (float4v){0.f,0.f,0.f,0.f};

    float* attnW = Out + (size_t)BN*HN*NN*DD
                 + (bh * NN + qw + lg) * (size_t)NN + vc;

    #pragma unroll
    for(int i = 0; i < 2; ++i)
        kreg[i] = *(const float4v*)(Kg + (size_t)(srow + 32*i) * DD + scol);
    #pragma unroll
    for(int i = 0; i < 2; ++i){            // stage tile 0 -> buf 0
        uint2v t = { cvt_pk_bf16(kreg[i][0], kreg[i][1]),
                     cvt_pk_bf16(kreg[i][2], kreg[i][3]) };
        *(uint2v*)&Kb[0][srow + 32*i][scol] = t;
    }
    #pragma unroll
    for(int i = 0; i < 2; ++i)             // load tile 1
        kreg[i] = *(const float4v*)(Kg + (size_t)(KT + srow + 32*i) * DD + scol);
    #pragma unroll
    for(int it = 0; it < 4; ++it)
        bv[it] = *(const float4v*)(BgV + (size_t)(it * 4) * NN);
    barrier_lds();

    for(int ct = 0; ct < NT; ++ct){
        const int cur = ct & 1;

        // V^T frags for tile t: 8 x dwordx4, each wave-contiguous 1KB, L2-resident.
        // Issued first so ~L2 latency hides under staging + QK MFMA + softmax.
        short8 vf[8];
        #pragma unroll
        for(int s = 0; s < 8; ++s)
            vf[s] = __builtin_bit_cast(short8,
                *(const uint4v*)(vtB + ((size_t)ct * 8 + s) * 512));

        if(ct + 1 < NT){                   // stage K t+1
            #pragma unroll
            for(int i = 0; i < 2; ++i){
                uint2v t = { cvt_pk_bf16(kreg[i][0], kreg[i][1]),
                             cvt_pk_bf16(kreg[i][2], kreg[i][3]) };
                *(uint2v*)&Kb[cur ^ 1][srow + 32*i][scol] = t;
            }
        }
        if(ct + 2 < NT){                   // load K t+2
            #pragma unroll
            for(int i = 0; i < 2; ++i)
                kreg[i] = *(const float4v*)(Kg + (size_t)((ct+2)*KT + srow + 32*i) * DD + scol);
        }
        #pragma unroll
        for(int it = 0; it < 4; ++it)      // stage bias(t) (wave-private)
            *(float4v*)&Pb[w][it*4 + lg][vc] = bv[it];
        if(ct + 1 < NT){
            #pragma unroll
            for(int it = 0; it < 4; ++it)
                bv[it] = *(const float4v*)(BgV + (size_t)(it * 4) * NN + (ct+1)*KT);
        }

        float4v acc[4];
        #pragma unroll
        for(int sub = 0; sub < 4; ++sub) acc[sub] = (float4v){0.f,0.f,0.f,0.f};
        __builtin_amdgcn_s_setprio(1);
        #pragma unroll
        for(int sub = 0; sub < 4; ++sub){
            short8 b0 = *(const short8*)&Kb[cur][sub*16 + ll][lg*8];
            short8 b1 = *(const short8*)&Kb[cur][sub*16 + ll][32 + lg*8];
            acc[sub] = mfma_bf16(qf[0], b0, acc[sub]);
            acc[sub] = mfma_bf16(qf[1], b1, acc[sub]);
        }
        __builtin_amdgcn_s_setprio(0);

        // ---- K-half pipelined softmax/PV bridge ----
        #pragma unroll
        for(int sub = 0; sub < 2; ++sub)
            #pragma unroll
            for(int r = 0; r < 4; ++r){
                float sv = acc[sub][r] * 0.125f + Pb[w][lg*4+r][sub*16+ll];
                Pb[w][lg*4+r][sub*16+ll] = __expf(sv) * rl[r];
            }
        lgkm_drain();

        short8 pf0;
        {
            float4v p0 = *(const float4v*)&Pb[w][ll][lg*8];
            float4v p1 = *(const float4v*)&Pb[w][ll][lg*8 + 4];
            pf0 = pack8(p0, p1);
        }
        #pragma unroll
        for(int sub = 2; sub < 4; ++sub)
            #pragma unroll
            for(int r = 0; r < 4; ++r){
                float sv = acc[sub][r] * 0.125f + Pb[w][lg*4+r][sub*16+ll];
                Pb[w][lg*4+r][sub*16+ll] = __expf(sv) * rl[r];
            }

        // PV kb=0 while subs 2,3 softmax retires
        __builtin_amdgcn_s_setprio(1);
        #pragma unroll
        for(int ds = 0; ds < 4; ++ds)
            oacc[ds] = mfma_bf16(pf0, vf[ds*2+0], oacc[ds]);
        __builtin_amdgcn_s_setprio(0);
        lgkm_drain();

        short8 pf1;
        {
            float4v p2 = *(const float4v*)&Pb[w][ll][32 + lg*8];
            float4v p3 = *(const float4v*)&Pb[w][ll][32 + lg*8 + 4];
            pf1 = pack8(p2, p3);
        }
        __builtin_amdgcn_s_setprio(1);
        #pragma unroll
        for(int ds = 0; ds < 4; ++ds)
            oacc[ds] = mfma_bf16(pf1, vf[ds*2+1], oacc[ds]);
        __builtin_amdgcn_s_setprio(0);

        // attn store last: all 64 cols of Pb hold p (drained above)
        #pragma unroll
        for(int it = 0; it < 4; ++it){
            float4v pv = *(const float4v*)&Pb[w][it*4 + lg][vc];
            *(float4v*)(attnW + (size_t)(it*4) * NN + ct*KT) = pv;
        }

        barrier_lds();                     // publishes Kb[cur^1]
    }

    // O store
    float* outG = Out + (bh * NN + qw) * (size_t)DD;
    #pragma unroll
    for(int ds = 0; ds < 4; ++ds)
        #pragma unroll
        for(int r = 0; r < 4; ++r)
            outG[(size_t)(lg*4 + r) * DD + ds*16 + ll] = oacc[ds][r];
}

extern "C" void kernel_launch(void* const* d_in, const int* in_sizes, int n_in,
                              void* d_out, int out_size, void* d_ws, size_t ws_size,
                              hipStream_t stream) {
    const float* q    = (const float*)d_in[0];
    const float* k    = (const float*)d_in[1];
    const float* v    = (const float*)d_in[2];
    const float* bias = (const float*)d_in[3];
    float* out = (float*)d_out;
    unsigned short* vtw = (unsigned short*)d_ws;   // 8.4 MB (ws >= 16.8 MB verified R11)

    hipLaunchKernelGGL(transpose_v_frag, dim3(BN * HN * (NN / 64)), dim3(256), 0, stream,
                       v, vtw);
    hipLaunchKernelGGL(attn_fused_kernel, dim3(BN * HN * (NN / QB)), dim3(512), 0, stream,
                       q, k, bias, vtw, out);
}

// Round 18
// 285.725 us; speedup vs baseline: 1.2056x; 1.1223x over previous
//
#include <hip/hip_runtime.h>
#include <cstdint>

#define BN 2
#define HN 16
#define NN 2048
#define DD 64
#define KT 64
#define NT (NN / KT)     // 32 tiles
#define QB 128           // q-rows per block (8 waves x 16)
#define LDP 72           // bf16 LDS row stride (Kb/Vt)
#define LDF 68           // fp32 LDS row stride (Pb)
#define KVELEMS ((size_t)BN * HN * NN * DD)   // 4,194,304 bf16 elems per ws region

typedef __attribute__((ext_vector_type(8))) short short8;
typedef __attribute__((ext_vector_type(2))) uint32_t uint2v;
typedef __attribute__((ext_vector_type(4))) uint32_t uint4v;
typedef __attribute__((ext_vector_type(4))) float float4v;

// packed f32->bf16 (RTNE), 2 elems / instr
static __device__ __forceinline__ uint32_t cvt_pk_bf16(float a, float b){
    uint32_t r;
    asm("v_cvt_pk_bf16_f32 %0, %1, %2" : "=v"(r) : "v"(a), "v"(b));
    return r;
}
static __device__ __forceinline__ unsigned short f2bf1(float a){
    return (unsigned short)(cvt_pk_bf16(a, a) & 0xffffu);
}
static __device__ __forceinline__ short8 pack8(float4v f0, float4v f1){
    uint4v u;
    u[0] = cvt_pk_bf16(f0[0], f0[1]);
    u[1] = cvt_pk_bf16(f0[2], f0[3]);
    u[2] = cvt_pk_bf16(f1[0], f1[1]);
    u[3] = cvt_pk_bf16(f1[2], f1[3]);
    return __builtin_bit_cast(short8, u);
}

static __device__ __forceinline__ float4v mfma_bf16(short8 a, short8 b, float4v c){
    return __builtin_amdgcn_mfma_f32_16x16x32_bf16(a, b, c, 0, 0, 0);
}

// Raw barrier: drain LDS ops only; global loads/stores stay in flight.
static __device__ __forceinline__ void barrier_lds(){
    asm volatile("s_waitcnt lgkmcnt(0)" ::: "memory");
    __builtin_amdgcn_s_barrier();
    asm volatile("" ::: "memory");
}
static __device__ __forceinline__ void lgkm_drain(){
    asm volatile("s_waitcnt lgkmcnt(0)" ::: "memory");
}

// ===== pre-pass A: K (fp32) -> bf16, linear (verified R11) =====
__global__ void convert_k_kernel(const float* __restrict__ K,
                                 unsigned short* __restrict__ KW){
    size_t i = ((size_t)blockIdx.x * 256 + threadIdx.x) * 8;
    float4v a = *(const float4v*)(K + i);
    float4v b = *(const float4v*)(K + i + 4);
    uint4v u;
    u[0] = cvt_pk_bf16(a[0], a[1]);
    u[1] = cvt_pk_bf16(a[2], a[3]);
    u[2] = cvt_pk_bf16(b[0], b[1]);
    u[3] = cvt_pk_bf16(b[2], b[3]);
    *(uint4v*)(KW + i) = u;
}

// ===== pre-pass B: V (fp32 [bh][kv][d]) -> V^T bf16 [bh][d][kv] (verified R11) =====
__global__ void transpose_v_kernel(const float* __restrict__ V,
                                   unsigned short* __restrict__ VTW){
    __shared__ unsigned short T[64][72];
    const int bid = blockIdx.x;
    const int bh  = bid >> 5;
    const int ct  = bid & 31;
    const int tid = threadIdx.x;

    const float* src = V + ((size_t)bh * NN + ct * 64) * DD;
    const int srow = tid >> 4;
    const int scol = (tid & 15) << 2;
    #pragma unroll
    for(int i = 0; i < 4; ++i){
        const int row = srow + 16 * i;
        float4v f = *(const float4v*)(src + (size_t)row * DD + scol);
        #pragma unroll
        for(int j = 0; j < 4; ++j)
            T[scol + j][row] = f2bf1(f[j]);
    }
    __syncthreads();
    unsigned short* dst = VTW + (size_t)bh * DD * NN + ct * 64;
    const int d  = tid >> 2;
    const int kc = (tid & 3) << 4;
    *(uint4v*)(dst + (size_t)d * NN + kc)     = *(const uint4v*)&T[d][kc];
    *(uint4v*)(dst + (size_t)d * NN + kc + 8) = *(const uint4v*)&T[d][kc + 8];
}

// 512 threads, 2 blocks/CU. VGPR cap 128 (R9 lesson: never force below natural).
__launch_bounds__(512, 4)
__global__ void attn_fused_kernel(const float* __restrict__ Q,
                                  const unsigned short* __restrict__ KW,
                                  const float* __restrict__ Bias,
                                  const unsigned short* __restrict__ VTW,
                                  float* __restrict__ Out){
    __shared__ unsigned short Kb[2][KT][LDP];   // double-buffered K tile [kv][d]
    __shared__ unsigned short Vt[2][DD][LDP];   // double-buffered V^T tile [d][kv] (linear)
    __shared__ float Pb[8][16][LDF];            // per-wave bias/P bounce (fp32, wave-private)

    // XCD-aware decode: slot raw&7 owns 2 whole heads (bias/K/V^T L2-resident).
    const int raw  = blockIdx.x;
    const int slot = raw & 7;
    const int idx  = raw >> 3;            // 0..63
    const int h    = slot * 2 + (idx >> 5);
    const int rem  = idx & 31;
    const int b    = rem & 1;             // batch pair adjacent -> shares bias slice
    const int rt   = rem >> 1;            // 0..15

    const int tid = threadIdx.x;
    const int l   = tid & 63;
    const int w   = tid >> 6;             // wave 0..7
    const int lg  = l >> 4;               // acc-layout row group
    const int ll  = l & 15;               // acc-layout col
    const int vc  = ll * 4;               // vec-layout col

    // bf16 staging coords: 512 threads x 16B cover the full 64x64 bf16 tile
    const int sKrow = tid >> 3;           // 0..63
    const int sKcol = (tid & 7) << 3;     // bf16 elem col 0..56

    const int qw = rt * QB + w * 16;
    const size_t bh = (size_t)(b * HN + h);
    const float* Qg = Q + (bh * NN + qw) * DD;
    const unsigned short* KgW = KW  + bh * NN * DD;   // [kv][d] bf16
    const unsigned short* VgW = VTW + bh * DD * NN;   // [d][kv] bf16
    // vec-layout bias base: lane covers rows qw+lg+4*it, cols vc..vc+3
    const float* BgV = Bias + (size_t)h * NN * NN + (size_t)(qw + lg) * NN + vc;

    // ---- Q fragments (A-frag: row=ll, k=ks*32+lg*8+j) ----
    short8 qf[2];
    {
        const float* qrow = Qg + (size_t)ll * DD + lg * 8;
        #pragma unroll
        for(int ks = 0; ks < 2; ++ks)
            qf[ks] = pack8(*(const float4v*)(qrow + ks * 32),
                           *(const float4v*)(qrow + ks * 32 + 4));
    }

    float lsum[4];
    #pragma unroll
    for(int r = 0; r < 4; ++r) lsum[r] = 0.f;

    // =============== PASS 1: row sums; Kb double-buffered, 1 barrier/tile ===============
    float4v bv[4];
    uint4v kreg;
    kreg = *(const uint4v*)(KgW + (size_t)sKrow * DD + sKcol);
    *(uint4v*)&Kb[0][sKrow][sKcol] = kreg;                      // stage tile 0
    kreg = *(const uint4v*)(KgW + (size_t)(KT + sKrow) * DD + sKcol);   // load tile 1
    #pragma unroll
    for(int it = 0; it < 4; ++it)
        bv[it] = *(const float4v*)(BgV + (size_t)(it * 4) * NN);
    barrier_lds();

    for(int ct = 0; ct < NT; ++ct){
        const int cur = ct & 1;
        if(ct + 1 < NT)                    // stage t+1 into other buffer (1 b128)
            *(uint4v*)&Kb[cur ^ 1][sKrow][sKcol] = kreg;
        if(ct + 2 < NT)                    // load t+2
            kreg = *(const uint4v*)(KgW + (size_t)((ct+2)*KT + sKrow) * DD + sKcol);
        #pragma unroll
        for(int it = 0; it < 4; ++it)      // stage bias(t) (Pb wave-private)
            *(float4v*)&Pb[w][it*4 + lg][vc] = bv[it];
        if(ct + 1 < NT){
            #pragma unroll
            for(int it = 0; it < 4; ++it)
                bv[it] = *(const float4v*)(BgV + (size_t)(it * 4) * NN + (ct+1)*KT);
        }

        float4v acc[4];
        #pragma unroll
        for(int sub = 0; sub < 4; ++sub) acc[sub] = (float4v){0.f,0.f,0.f,0.f};
        __builtin_amdgcn_s_setprio(1);
        #pragma unroll
        for(int sub = 0; sub < 4; ++sub){
            short8 b0 = *(const short8*)&Kb[cur][sub*16 + ll][lg*8];
            short8 b1 = *(const short8*)&Kb[cur][sub*16 + ll][32 + lg*8];
            acc[sub] = mfma_bf16(qf[0], b0, acc[sub]);
            acc[sub] = mfma_bf16(qf[1], b1, acc[sub]);
        }
        __builtin_amdgcn_s_setprio(0);

        #pragma unroll
        for(int r = 0; r < 4; ++r){
            float e0 = __expf(acc[0][r] * 0.125f + Pb[w][lg*4+r][      ll]);
            float e1 = __expf(acc[1][r] * 0.125f + Pb[w][lg*4+r][16 +  ll]);
            float e2 = __expf(acc[2][r] * 0.125f + Pb[w][lg*4+r][32 +  ll]);
            float e3 = __expf(acc[3][r] * 0.125f + Pb[w][lg*4+r][48 +  ll]);
            lsum[r] += (e0 + e1) + (e2 + e3);
        }
        barrier_lds();                     // publishes buf[cur^1]
    }

    float rl[4];
    #pragma unroll
    for(int r = 0; r < 4; ++r){
        #pragma unroll
        for(int d = 1; d < 16; d <<= 1) lsum[r] += __shfl_xor(lsum[r], d);
        rl[r] = 1.0f / lsum[r];
    }

    // ========= PASS 2: pipelined softmax/PV; Kb/Vt dbuf (b128 staging), 1 barrier =========
    float4v oacc[4];
    #pragma unroll
    for(int ds = 0; ds < 4; ++ds) oacc[ds] = (float4v){0.f,0.f,0.f,0.f};

    float* attnW = Out + (size_t)BN*HN*NN*DD
                 + (bh * NN + qw + lg) * (size_t)NN + vc;

    uint4v vreg;
    kreg = *(const uint4v*)(KgW + (size_t)sKrow * DD + sKcol);
    vreg = *(const uint4v*)(VgW + (size_t)sKrow * NN + sKcol);
    *(uint4v*)&Kb[0][sKrow][sKcol] = kreg;                      // stage tile 0
    *(uint4v*)&Vt[0][sKrow][sKcol] = vreg;
    kreg = *(const uint4v*)(KgW + (size_t)(KT + sKrow) * DD + sKcol);   // load tile 1
    vreg = *(const uint4v*)(VgW + (size_t)sKrow * NN + KT + sKcol);
    #pragma unroll
    for(int it = 0; it < 4; ++it)
        bv[it] = *(const float4v*)(BgV + (size_t)(it * 4) * NN);
    barrier_lds();

    for(int ct = 0; ct < NT; ++ct){
        const int cur = ct & 1;
        if(ct + 1 < NT){                   // stage t+1 (2 x b128)
            *(uint4v*)&Kb[cur ^ 1][sKrow][sKcol] = kreg;
            *(uint4v*)&Vt[cur ^ 1][sKrow][sKcol] = vreg;
        }
        if(ct + 2 < NT){                   // load t+2
            kreg = *(const uint4v*)(KgW + (size_t)((ct+2)*KT + sKrow) * DD + sKcol);
            vreg = *(const uint4v*)(VgW + (size_t)sKrow * NN + (ct+2)*KT + sKcol);
        }
        #pragma unroll
        for(int it = 0; it < 4; ++it)      // stage bias(t) (wave-private)
            *(float4v*)&Pb[w][it*4 + lg][vc] = bv[it];
        if(ct + 1 < NT){
            #pragma unroll
            for(int it = 0; it < 4; ++it)
                bv[it] = *(const float4v*)(BgV + (size_t)(it * 4) * NN + (ct+1)*KT);
        }

        float4v acc[4];
        #pragma unroll
        for(int sub = 0; sub < 4; ++sub) acc[sub] = (float4v){0.f,0.f,0.f,0.f};
        __builtin_amdgcn_s_setprio(1);
        #pragma unroll
        for(int sub = 0; sub < 4; ++sub){
            short8 b0 = *(const short8*)&Kb[cur][sub*16 + ll][lg*8];
            short8 b1 = *(const short8*)&Kb[cur][sub*16 + ll][32 + lg*8];
            acc[sub] = mfma_bf16(qf[0], b0, acc[sub]);
            acc[sub] = mfma_bf16(qf[1], b1, acc[sub]);
        }
        __builtin_amdgcn_s_setprio(0);

        // ---- K-half pipelined softmax/PV bridge (validated R15) ----
        #pragma unroll
        for(int sub = 0; sub < 2; ++sub)
            #pragma unroll
            for(int r = 0; r < 4; ++r){
                float sv = acc[sub][r] * 0.125f + Pb[w][lg*4+r][sub*16+ll];
                Pb[w][lg*4+r][sub*16+ll] = __expf(sv) * rl[r];
            }
        lgkm_drain();

        short8 pf0;
        {
            float4v p0 = *(const float4v*)&Pb[w][ll][lg*8];
            float4v p1 = *(const float4v*)&Pb[w][ll][lg*8 + 4];
            pf0 = pack8(p0, p1);
        }
        #pragma unroll
        for(int sub = 2; sub < 4; ++sub)
            #pragma unroll
            for(int r = 0; r < 4; ++r){
                float sv = acc[sub][r] * 0.125f + Pb[w][lg*4+r][sub*16+ll];
                Pb[w][lg*4+r][sub*16+ll] = __expf(sv) * rl[r];
            }

        // PV kb=0 while subs 2,3 softmax retires (Vt reads now linear, no swizzle)
        __builtin_amdgcn_s_setprio(1);
        #pragma unroll
        for(int ds = 0; ds < 4; ++ds){
            short8 v0 = *(const short8*)&Vt[cur][ds*16 + ll][lg*8];
            oacc[ds] = mfma_bf16(pf0, v0, oacc[ds]);
        }
        __builtin_amdgcn_s_setprio(0);
        lgkm_drain();

        short8 pf1;
        {
            float4v p2 = *(const float4v*)&Pb[w][ll][32 + lg*8];
            float4v p3 = *(const float4v*)&Pb[w][ll][32 + lg*8 + 4];
            pf1 = pack8(p2, p3);
        }
        __builtin_amdgcn_s_setprio(1);
        #pragma unroll
        for(int ds = 0; ds < 4; ++ds){
            short8 v1 = *(const short8*)&Vt[cur][ds*16 + ll][32 + lg*8];
            oacc[ds] = mfma_bf16(pf1, v1, oacc[ds]);
        }
        __builtin_amdgcn_s_setprio(0);

        // attn store last: all 64 cols of Pb hold p (drained above)
        #pragma unroll
        for(int it = 0; it < 4; ++it){
            float4v pv = *(const float4v*)&Pb[w][it*4 + lg][vc];
            *(float4v*)(attnW + (size_t)(it*4) * NN + ct*KT) = pv;
        }

        barrier_lds();                     // publishes buf[cur^1]
    }

    // O store
    float* outG = Out + (bh * NN + qw) * (size_t)DD;
    #pragma unroll
    for(int ds = 0; ds < 4; ++ds)
        #pragma unroll
        for(int r = 0; r < 4; ++r)
            outG[(size_t)(lg*4 + r) * DD + ds*16 + ll] = oacc[ds][r];
}

extern "C" void kernel_launch(void* const* d_in, const int* in_sizes, int n_in,
                              void* d_out, int out_size, void* d_ws, size_t ws_size,
                              hipStream_t stream) {
    const float* q    = (const float*)d_in[0];
    const float* k    = (const float*)d_in[1];
    const float* v    = (const float*)d_in[2];
    const float* bias = (const float*)d_in[3];
    float* out = (float*)d_out;
    unsigned short* kw  = (unsigned short*)d_ws;          // 8.4 MB
    unsigned short* vtw = kw + KVELEMS;                   // 8.4 MB (ws >= 16.8 MB, verified R11)

    hipLaunchKernelGGL(convert_k_kernel, dim3(KVELEMS / 8 / 256), dim3(256), 0, stream,
                       k, kw);
    hipLaunchKernelGGL(transpose_v_kernel, dim3(BN * HN * (NN / 64)), dim3(256), 0, stream,
                       v, vtw);
    hipLaunchKernelGGL(attn_fused_kernel, dim3(BN * HN * (NN / QB)), dim3(512), 0, stream,
                       q, kw, bias, vtw, out);
}